// Round 1
// baseline (187.781 us; speedup 1.0000x reference)
//
#include <hip/hip_runtime.h>
#include <hip/hip_bf16.h>

#define BATCH 8
#define CCH   512
#define NHD   8
#define HD    64
#define LLEN  4096
#define M1    1536

typedef __bf16 bf16x8 __attribute__((ext_vector_type(8)));
typedef __bf16 bf16x4 __attribute__((ext_vector_type(4)));
typedef float  f32x4  __attribute__((ext_vector_type(4)));

__device__ __forceinline__ f32x4 mfma16(bf16x8 a, bf16x8 b, f32x4 c) {
  return __builtin_amdgcn_mfma_f32_16x16x32_bf16(a, b, c, 0, 0, 0);
}

// ---------------- pack weights/biases to bf16 ----------------
__global__ void pack_w(const float* __restrict__ wq, const float* __restrict__ wk,
                       const float* __restrict__ wv, const float* __restrict__ wo,
                       const float* __restrict__ bq, const float* __restrict__ bk,
                       const float* __restrict__ bv,
                       __bf16* __restrict__ wqkvb, __bf16* __restrict__ wob,
                       float* __restrict__ biasq) {
  const int n = M1 * CCH + CCH * CCH + M1;
  for (int i = blockIdx.x * blockDim.x + threadIdx.x; i < n; i += gridDim.x * blockDim.x) {
    if (i < M1 * CCH) {
      int r = i >> 9, c = i & 511;
      float v = (r < 512) ? wq[r * 512 + c]
              : (r < 1024) ? wk[(r - 512) * 512 + c]
                           : wv[(r - 1024) * 512 + c];
      wqkvb[i] = (__bf16)v;
    } else if (i < M1 * CCH + CCH * CCH) {
      int j = i - M1 * CCH;
      wob[j] = (__bf16)wo[j];
    } else {
      int j = i - M1 * CCH - CCH * CCH;
      biasq[j] = (j < 512) ? bq[j] : (j < 1024) ? bk[j - 512] : bv[j - 1024];
    }
  }
}

// ---------------- x [b][C][L] fp32 -> xt [b][L][C] bf16 ----------------
__global__ void transpose_x(const float* __restrict__ x, __bf16* __restrict__ xt) {
  __shared__ float tile[32][33];
  const int b = blockIdx.z, c0 = blockIdx.y * 32, l0 = blockIdx.x * 32;
  const int tx = threadIdx.x & 31, ty = threadIdx.x >> 5;  // ty 0..7
  const float* xp = x + ((size_t)b * CCH + c0) * LLEN + l0;
#pragma unroll
  for (int j = 0; j < 4; ++j)
    tile[ty + j * 8][tx] = xp[(size_t)(ty + j * 8) * LLEN + tx];
  __syncthreads();
  __bf16* xo = xt + ((size_t)b * LLEN + l0) * CCH + c0;
#pragma unroll
  for (int j = 0; j < 4; ++j)
    xo[(size_t)(ty + j * 8) * CCH + tx] = (__bf16)tile[tx][ty + j * 8];
}

// ---------------- GEMM: D[m][n] = A[M][512] * B[b][n][k] (k-major rows) ----------------
// EPI 0: QKV epilogue (bias + elu+1 on Q/K; write qt [b][l][c], kcm/vcm [b][c][l])
// EPI 1: output epilogue (bias; write fp32 out [b][c][l])
template <int EPI>
__global__ __launch_bounds__(256) void gemm_k(
    const __bf16* __restrict__ A, const __bf16* __restrict__ Bm,
    const float* __restrict__ bias,
    __bf16* __restrict__ qt, __bf16* __restrict__ kcm, __bf16* __restrict__ vcm,
    float* __restrict__ out) {
  __shared__ __attribute__((aligned(16))) __bf16 As[128 * 36];
  __shared__ __attribute__((aligned(16))) __bf16 Bs[128 * 36];
  const int b  = blockIdx.z;
  const int n0 = blockIdx.x * 128;
  const int m0 = blockIdx.y * 128;
  const int tid = threadIdx.x;
  const int ll = tid & 63, w = tid >> 6;
  const int wr = w >> 1, wc = w & 1;
  const int lhi = ll >> 4, llo = ll & 15;

  const __bf16* Bp = Bm + ((size_t)b * LLEN + n0) * CCH;

  f32x4 acc[4][4];
#pragma unroll
  for (int i = 0; i < 4; ++i)
#pragma unroll
    for (int j = 0; j < 4; ++j) acc[i][j] = (f32x4){0.f, 0.f, 0.f, 0.f};

  for (int kt = 0; kt < 16; ++kt) {
    const int k0 = kt * 32;
    if (kt) __syncthreads();
#pragma unroll
    for (int j = 0; j < 2; ++j) {
      int idx = tid + j * 256;
      int row = idx >> 2, c8 = (idx & 3) * 8;
      bf16x8 va = *(const bf16x8*)(A + (size_t)(m0 + row) * CCH + k0 + c8);
      *(bf16x4*)(As + row * 36 + c8)     = ((bf16x4*)&va)[0];
      *(bf16x4*)(As + row * 36 + c8 + 4) = ((bf16x4*)&va)[1];
      bf16x8 vb = *(const bf16x8*)(Bp + (size_t)row * CCH + k0 + c8);
      *(bf16x4*)(Bs + row * 36 + c8)     = ((bf16x4*)&vb)[0];
      *(bf16x4*)(Bs + row * 36 + c8 + 4) = ((bf16x4*)&vb)[1];
    }
    __syncthreads();
    bf16x8 af[4], bfr[4];
#pragma unroll
    for (int i = 0; i < 4; ++i) {
      const __bf16* pa = As + (wr * 64 + i * 16 + llo) * 36 + lhi * 8;
      ((bf16x4*)&af[i])[0] = *(const bf16x4*)pa;
      ((bf16x4*)&af[i])[1] = *(const bf16x4*)(pa + 4);
      const __bf16* pb = Bs + (wc * 64 + i * 16 + llo) * 36 + lhi * 8;
      ((bf16x4*)&bfr[i])[0] = *(const bf16x4*)pb;
      ((bf16x4*)&bfr[i])[1] = *(const bf16x4*)(pb + 4);
    }
#pragma unroll
    for (int i = 0; i < 4; ++i)
#pragma unroll
      for (int j = 0; j < 4; ++j) acc[i][j] = mfma16(af[i], bfr[j], acc[i][j]);
  }

  // epilogue
#pragma unroll
  for (int i = 0; i < 4; ++i) {
    const int o0 = m0 + wr * 64 + i * 16 + lhi * 4;
#pragma unroll
    for (int j = 0; j < 4; ++j) {
      const int col = n0 + wc * 64 + j * 16 + llo;
      if (EPI == 0) {
        if (m0 < 512) {
          bf16x4 pk;
#pragma unroll
          for (int r = 0; r < 4; ++r) {
            float t = acc[i][j][r] + bias[o0 + r];
            t = t > 0.f ? t + 1.f : __expf(t);
            pk[r] = (__bf16)t;
          }
          *(bf16x4*)(qt + ((size_t)b * LLEN + col) * CCH + o0) = pk;
        } else if (m0 < 1024) {
#pragma unroll
          for (int r = 0; r < 4; ++r) {
            float t = acc[i][j][r] + bias[o0 + r];
            t = t > 0.f ? t + 1.f : __expf(t);
            kcm[((size_t)b * CCH + (o0 - 512 + r)) * LLEN + col] = (__bf16)t;
          }
        } else {
#pragma unroll
          for (int r = 0; r < 4; ++r)
            vcm[((size_t)b * CCH + (o0 - 1024 + r)) * LLEN + col] =
                (__bf16)(acc[i][j][r] + bias[o0 + r]);
        }
      } else {
#pragma unroll
        for (int r = 0; r < 4; ++r)
          out[((size_t)b * CCH + o0 + r) * LLEN + col] = acc[i][j][r] + bias[o0 + r];
      }
    }
  }
}

// ---------------- Ksum[b*512+c] = sum_l kcm[b][c][l] ----------------
__global__ void ksum_k(const __bf16* __restrict__ kcm, float* __restrict__ ksum) {
  const int bid = blockIdx.x;
  const __bf16* p = kcm + (size_t)bid * LLEN;
  const int t = threadIdx.x;
  float s = 0.f;
  bf16x8 v0 = *(const bf16x8*)(p + t * 16);
  bf16x8 v1 = *(const bf16x8*)(p + t * 16 + 8);
#pragma unroll
  for (int i = 0; i < 8; ++i) s += (float)v0[i] + (float)v1[i];
  for (int off = 32; off; off >>= 1) s += __shfl_down(s, off);
  __shared__ float sw[4];
  if ((t & 63) == 0) sw[t >> 6] = s;
  __syncthreads();
  if (t == 0) ksum[bid] = sw[0] + sw[1] + sw[2] + sw[3];
}

// ---------------- KV partials: part[lc][bh][d][v] = sum_{l in chunk} K[d][l]V[v][l] ----------------
__global__ __launch_bounds__(64) void kv_part_k(const __bf16* __restrict__ kcm,
                                                const __bf16* __restrict__ vcm,
                                                float* __restrict__ part) {
  const int lc = blockIdx.x, bh = blockIdx.y;
  const int b = bh >> 3, h = bh & 7;
  const int ll = threadIdx.x, lhi = ll >> 4, llo = ll & 15;
  const __bf16* Kp = kcm + ((size_t)b * CCH + h * 64) * LLEN;
  const __bf16* Vp = vcm + ((size_t)b * CCH + h * 64) * LLEN;
  f32x4 acc[4][4];
#pragma unroll
  for (int i = 0; i < 4; ++i)
#pragma unroll
    for (int j = 0; j < 4; ++j) acc[i][j] = (f32x4){0.f, 0.f, 0.f, 0.f};
  const int base = lc * 512 + lhi * 8;
  for (int kt = 0; kt < 16; ++kt) {
    const int k0 = base + kt * 32;
    bf16x8 af[4], bfr[4];
#pragma unroll
    for (int i = 0; i < 4; ++i) af[i]  = *(const bf16x8*)(Kp + (size_t)(i * 16 + llo) * LLEN + k0);
#pragma unroll
    for (int i = 0; i < 4; ++i) bfr[i] = *(const bf16x8*)(Vp + (size_t)(i * 16 + llo) * LLEN + k0);
#pragma unroll
    for (int i = 0; i < 4; ++i)
#pragma unroll
      for (int j = 0; j < 4; ++j) acc[i][j] = mfma16(af[i], bfr[j], acc[i][j]);
  }
  float* op = part + ((size_t)lc * 64 + bh) * 4096;
#pragma unroll
  for (int i = 0; i < 4; ++i)
#pragma unroll
    for (int j = 0; j < 4; ++j)
#pragma unroll
      for (int r = 0; r < 4; ++r) {
        int d = i * 16 + lhi * 4 + r, v = j * 16 + llo;
        op[d * 64 + v] = acc[i][j][r];
      }
}

__global__ void kv_red_k(const float* __restrict__ part, float* __restrict__ kv) {
  const int i = blockIdx.x * blockDim.x + threadIdx.x;  // 0..262143
  float s = 0.f;
#pragma unroll
  for (int lc = 0; lc < 8; ++lc) s += part[(size_t)lc * 262144 + i];
  kv[i] = s;
}

// ---------------- apply: attn[b][l][h*64+v] = (sum_d Q[l,d]KV[d,v]) * Z[l] ----------------
__global__ __launch_bounds__(256) void apply_k(const __bf16* __restrict__ qt,
                                               const float* __restrict__ kv,
                                               const float* __restrict__ ksum,
                                               __bf16* __restrict__ attn) {
  __shared__ __attribute__((aligned(16))) __bf16 kvT[64 * 68];
  __shared__ float zb[256];
  const int lc = blockIdx.x, bh = blockIdx.y;
  const int b = bh >> 3, h = bh & 7;
  const int tid = threadIdx.x;
  // stage KV^T (bf16) into LDS: kvT[v][d]
  const float* kvp = kv + (size_t)bh * 4096;
  for (int i = tid; i < 4096; i += 256) {
    int d = i >> 6, v = i & 63;
    kvT[v * 68 + d] = (__bf16)kvp[i];
  }
  // Z for this thread's l
  const int l = lc * 256 + tid;
  const __bf16* qp = qt + ((size_t)b * LLEN + l) * CCH + h * 64;
  const float* ksp = ksum + bh * 64;  // == b*512 + h*64
  float s = 0.f;
#pragma unroll
  for (int d8 = 0; d8 < 64; d8 += 8) {
    bf16x8 qv = *(const bf16x8*)(qp + d8);
#pragma unroll
    for (int i = 0; i < 8; ++i) s += (float)qv[i] * ksp[d8 + i];
  }
  zb[tid] = 1.0f / (s + 1e-6f);
  __syncthreads();

  const int ll = tid & 63, w = tid >> 6, lhi = ll >> 4, llo = ll & 15;
  f32x4 acc[4][4];
#pragma unroll
  for (int i = 0; i < 4; ++i)
#pragma unroll
    for (int j = 0; j < 4; ++j) acc[i][j] = (f32x4){0.f, 0.f, 0.f, 0.f};
  const __bf16* qbase = qt + ((size_t)b * LLEN + lc * 256 + w * 64) * CCH + h * 64;
#pragma unroll
  for (int kt = 0; kt < 2; ++kt) {
    const int k8 = kt * 32 + lhi * 8;
    bf16x8 af[4], bfr[4];
#pragma unroll
    for (int i = 0; i < 4; ++i)
      af[i] = *(const bf16x8*)(qbase + (size_t)(i * 16 + llo) * CCH + k8);
#pragma unroll
    for (int j = 0; j < 4; ++j) {
      const __bf16* pb = kvT + (j * 16 + llo) * 68 + k8;
      ((bf16x4*)&bfr[j])[0] = *(const bf16x4*)pb;
      ((bf16x4*)&bfr[j])[1] = *(const bf16x4*)(pb + 4);
    }
#pragma unroll
    for (int i = 0; i < 4; ++i)
#pragma unroll
      for (int j = 0; j < 4; ++j) acc[i][j] = mfma16(af[i], bfr[j], acc[i][j]);
  }
  __bf16* ap = attn + ((size_t)b * LLEN + lc * 256) * CCH + h * 64;
#pragma unroll
  for (int i = 0; i < 4; ++i)
#pragma unroll
    for (int j = 0; j < 4; ++j)
#pragma unroll
      for (int r = 0; r < 4; ++r) {
        int ml = w * 64 + i * 16 + lhi * 4 + r;
        int v = j * 16 + llo;
        ap[(size_t)ml * CCH + v] = (__bf16)(acc[i][j][r] * zb[ml]);
      }
}

extern "C" void kernel_launch(void* const* d_in, const int* in_sizes, int n_in,
                              void* d_out, int out_size, void* d_ws, size_t ws_size,
                              hipStream_t stream) {
  const float* x  = (const float*)d_in[0];
  const float* wq = (const float*)d_in[1];
  const float* bq = (const float*)d_in[2];
  const float* wk = (const float*)d_in[3];
  const float* bk = (const float*)d_in[4];
  const float* wv = (const float*)d_in[5];
  const float* bv = (const float*)d_in[6];
  const float* wo = (const float*)d_in[7];
  const float* bo = (const float*)d_in[8];
  float* out = (float*)d_out;

  char* p = (char*)d_ws;
  __bf16* xt    = (__bf16*)p; p += (size_t)BATCH * LLEN * CCH * 2;  // 32MB (reused as attn)
  __bf16* qt    = (__bf16*)p; p += (size_t)BATCH * LLEN * CCH * 2;  // 32MB
  __bf16* kcm   = (__bf16*)p; p += (size_t)BATCH * CCH * LLEN * 2;  // 32MB
  __bf16* vcm   = (__bf16*)p; p += (size_t)BATCH * CCH * LLEN * 2;  // 32MB
  __bf16* wqkvb = (__bf16*)p; p += (size_t)M1 * CCH * 2;
  __bf16* wob   = (__bf16*)p; p += (size_t)CCH * CCH * 2;
  float*  biasq = (float*)p;  p += (size_t)M1 * 4;
  float*  ksum  = (float*)p;  p += (size_t)BATCH * CCH * 4;
  float*  part  = (float*)p;  p += (size_t)8 * 64 * HD * HD * 4;    // 8MB
  float*  kvb   = (float*)p;  p += (size_t)64 * HD * HD * 4;        // 1MB
  __bf16* attn  = xt;

  pack_w<<<1024, 256, 0, stream>>>(wq, wk, wv, wo, bq, bk, bv, wqkvb, wob, biasq);
  transpose_x<<<dim3(128, 16, BATCH), 256, 0, stream>>>(x, xt);
  gemm_k<0><<<dim3(32, 12, BATCH), 256, 0, stream>>>(wqkvb, xt, biasq, qt, kcm, vcm, nullptr);
  ksum_k<<<4096, 256, 0, stream>>>(kcm, ksum);
  kv_part_k<<<dim3(8, 64), 64, 0, stream>>>(kcm, vcm, part);
  kv_red_k<<<1024, 256, 0, stream>>>(part, kvb);
  apply_k<<<dim3(16, 64), 256, 0, stream>>>(qt, kvb, ksum, attn);
  gemm_k<1><<<dim3(32, 4, BATCH), 256, 0, stream>>>(wob, attn, bo, nullptr, nullptr, nullptr, out);
}

// Round 2
// 172.922 us; speedup vs baseline: 1.0859x; 1.0859x over previous
//
#include <hip/hip_runtime.h>
#include <hip/hip_bf16.h>
#include <stdint.h>

#define BATCH 8
#define CCH   512
#define NHD   8
#define HD    64
#define LLEN  4096
#define M1    1536

typedef __bf16 bf16x8 __attribute__((ext_vector_type(8)));
typedef __bf16 bf16x4 __attribute__((ext_vector_type(4)));
typedef float  f32x4  __attribute__((ext_vector_type(4)));

__device__ __forceinline__ f32x4 mfma16(bf16x8 a, bf16x8 b, f32x4 c) {
  return __builtin_amdgcn_mfma_f32_16x16x32_bf16(a, b, c, 0, 0, 0);
}

// async global->LDS, 16B per lane. LDS dest is wave-uniform base + lane*16.
__device__ __forceinline__ void gload_lds16(const void* g, void* l) {
  __builtin_amdgcn_global_load_lds(
      (const __attribute__((address_space(1))) uint32_t*)(uintptr_t)g,
      (__attribute__((address_space(3))) uint32_t*)(uintptr_t)l,
      16, 0, 0);
}

// ---------------- pack weights/biases to bf16 ----------------
__global__ void pack_w(const float* __restrict__ wq, const float* __restrict__ wk,
                       const float* __restrict__ wv, const float* __restrict__ wo,
                       const float* __restrict__ bq, const float* __restrict__ bk,
                       const float* __restrict__ bv,
                       __bf16* __restrict__ wqkvb, __bf16* __restrict__ wob,
                       float* __restrict__ biasq) {
  const int n = M1 * CCH + CCH * CCH + M1;
  for (int i = blockIdx.x * blockDim.x + threadIdx.x; i < n; i += gridDim.x * blockDim.x) {
    if (i < M1 * CCH) {
      int r = i >> 9, c = i & 511;
      float v = (r < 512) ? wq[r * 512 + c]
              : (r < 1024) ? wk[(r - 512) * 512 + c]
                           : wv[(r - 1024) * 512 + c];
      wqkvb[i] = (__bf16)v;
    } else if (i < M1 * CCH + CCH * CCH) {
      int j = i - M1 * CCH;
      wob[j] = (__bf16)wo[j];
    } else {
      int j = i - M1 * CCH - CCH * CCH;
      biasq[j] = (j < 512) ? bq[j] : (j < 1024) ? bk[j - 512] : bv[j - 1024];
    }
  }
}

// ---------------- x [b][C][L] fp32 -> xt [b][L][C] bf16 (64x64 tiles) ----------------
__global__ __launch_bounds__(256) void transpose_x(const float* __restrict__ x,
                                                   __bf16* __restrict__ xt) {
  __shared__ float tile[64][65];
  const int b = blockIdx.z, c0 = blockIdx.y * 64, l0 = blockIdx.x * 64;
  const int t = threadIdx.x;
  // read: 16 c-rows per pass, float4 along l
  const int lq = (t & 15) * 4, cr = t >> 4;
  const float* xp = x + ((size_t)b * CCH + c0) * LLEN + l0;
#pragma unroll
  for (int q = 0; q < 4; ++q) {
    const int c = cr + q * 16;
    float4 v = *(const float4*)(xp + (size_t)c * LLEN + lq);
    tile[c][lq + 0] = v.x;
    tile[c][lq + 1] = v.y;
    tile[c][lq + 2] = v.z;
    tile[c][lq + 3] = v.w;
  }
  __syncthreads();
  // write: bf16x4 along c
  __bf16* xo = xt + ((size_t)b * LLEN + l0) * CCH + c0;
  const int c4 = (t & 15) * 4, lr = t >> 4;
#pragma unroll
  for (int p = 0; p < 4; ++p) {
    const int l = lr + p * 16;
    bf16x4 o;
#pragma unroll
    for (int i = 0; i < 4; ++i) o[i] = (__bf16)tile[c4 + i][l];
    *(bf16x4*)(xo + (size_t)l * CCH + c4) = o;
  }
}

// ---------------- GEMM (m97 structure): D[m][n] = A[M][512] * B[b][n][k] ----------------
// EPI 0: QKV epilogue (bias + elu+1 on Q/K; write qt [b][l][c], kcm/vcm [b][c][l])
// EPI 1: output epilogue (bias; write fp32 out [b][c][l])
template <int EPI>
__global__ __launch_bounds__(256) void gemm_k(
    const __bf16* __restrict__ A, const __bf16* __restrict__ Bm,
    const float* __restrict__ bias,
    __bf16* __restrict__ qt, __bf16* __restrict__ kcm, __bf16* __restrict__ vcm,
    float* __restrict__ out) {
  __shared__ __attribute__((aligned(16))) __bf16 As[128 * 32];
  __shared__ __attribute__((aligned(16))) __bf16 Bs[128 * 32];
  const int b  = blockIdx.z;
  const int n0 = blockIdx.x * 128;
  const int m0 = blockIdx.y * 128;
  const int tid = threadIdx.x;
  const int ll = tid & 63, w = tid >> 6;
  const int wr = w >> 1, wc = w & 1;
  const int lhi = ll >> 4, llo = ll & 15;
  const int r4 = ll >> 2, c8e = (ll & 3) * 8;  // staging: lane -> (row, col8)

  const __bf16* Ap = A + (size_t)m0 * CCH;
  const __bf16* Bp = Bm + ((size_t)b * LLEN + n0) * CCH;

  f32x4 acc[4][4];
#pragma unroll
  for (int i = 0; i < 4; ++i)
#pragma unroll
    for (int j = 0; j < 4; ++j) acc[i][j] = (f32x4){0.f, 0.f, 0.f, 0.f};

  for (int kt = 0; kt < 16; ++kt) {
    const int k0 = kt * 32;
    if (kt) __syncthreads();
    // stage: 4 x global_load_lds_dwordx4 per thread (A:2, B:2); wave-uniform LDS base
#pragma unroll
    for (int i = 0; i < 2; ++i) {
      const int rb = i * 64 + w * 16;
      gload_lds16(Ap + (size_t)(rb + r4) * CCH + k0 + c8e, As + rb * 32);
      gload_lds16(Bp + (size_t)(rb + r4) * CCH + k0 + c8e, Bs + rb * 32);
    }
    __syncthreads();
    bf16x8 af[4], bfr[4];
#pragma unroll
    for (int i = 0; i < 4; ++i) {
      af[i]  = *(const bf16x8*)(As + (wr * 64 + i * 16 + llo) * 32 + lhi * 8);
      bfr[i] = *(const bf16x8*)(Bs + (wc * 64 + i * 16 + llo) * 32 + lhi * 8);
    }
#pragma unroll
    for (int i = 0; i < 4; ++i)
#pragma unroll
      for (int j = 0; j < 4; ++j) acc[i][j] = mfma16(af[i], bfr[j], acc[i][j]);
  }

  // epilogue
#pragma unroll
  for (int i = 0; i < 4; ++i) {
    const int o0 = m0 + wr * 64 + i * 16 + lhi * 4;
#pragma unroll
    for (int j = 0; j < 4; ++j) {
      const int col = n0 + wc * 64 + j * 16 + llo;
      if (EPI == 0) {
        if (m0 < 512) {
          bf16x4 pk;
#pragma unroll
          for (int r = 0; r < 4; ++r) {
            float t = acc[i][j][r] + bias[o0 + r];
            t = t > 0.f ? t + 1.f : __expf(t);
            pk[r] = (__bf16)t;
          }
          *(bf16x4*)(qt + ((size_t)b * LLEN + col) * CCH + o0) = pk;
        } else if (m0 < 1024) {
#pragma unroll
          for (int r = 0; r < 4; ++r) {
            float t = acc[i][j][r] + bias[o0 + r];
            t = t > 0.f ? t + 1.f : __expf(t);
            kcm[((size_t)b * CCH + (o0 - 512 + r)) * LLEN + col] = (__bf16)t;
          }
        } else {
#pragma unroll
          for (int r = 0; r < 4; ++r)
            vcm[((size_t)b * CCH + (o0 - 1024 + r)) * LLEN + col] =
                (__bf16)(acc[i][j][r] + bias[o0 + r]);
        }
      } else {
#pragma unroll
        for (int r = 0; r < 4; ++r)
          out[((size_t)b * CCH + o0 + r) * LLEN + col] = acc[i][j][r] + bias[o0 + r];
      }
    }
  }
}

// ---------------- KV partials + fused Ksum partials ----------------
// part[lc][bh][d][v] = sum_{l in chunk} K[d][l]V[v][l];  pks[lc][bh][d] = sum K[d][l]
__global__ __launch_bounds__(64) void kv_part_k(const __bf16* __restrict__ kcm,
                                                const __bf16* __restrict__ vcm,
                                                float* __restrict__ part,
                                                float* __restrict__ part_ks) {
  const int lc = blockIdx.x, bh = blockIdx.y;
  const int b = bh >> 3, h = bh & 7;
  const int ll = threadIdx.x, lhi = ll >> 4, llo = ll & 15;
  const __bf16* Kp = kcm + ((size_t)b * CCH + h * 64) * LLEN;
  const __bf16* Vp = vcm + ((size_t)b * CCH + h * 64) * LLEN;
  f32x4 acc[4][4];
#pragma unroll
  for (int i = 0; i < 4; ++i)
#pragma unroll
    for (int j = 0; j < 4; ++j) acc[i][j] = (f32x4){0.f, 0.f, 0.f, 0.f};
  float ks[4] = {0.f, 0.f, 0.f, 0.f};
  const int base = lc * 512 + lhi * 8;
  for (int kt = 0; kt < 16; ++kt) {
    const int k0 = base + kt * 32;
    bf16x8 af[4], bfr[4];
#pragma unroll
    for (int i = 0; i < 4; ++i) af[i]  = *(const bf16x8*)(Kp + (size_t)(i * 16 + llo) * LLEN + k0);
#pragma unroll
    for (int i = 0; i < 4; ++i) bfr[i] = *(const bf16x8*)(Vp + (size_t)(i * 16 + llo) * LLEN + k0);
#pragma unroll
    for (int i = 0; i < 4; ++i)
#pragma unroll
      for (int r = 0; r < 8; ++r) ks[i] += (float)af[i][r];
#pragma unroll
    for (int i = 0; i < 4; ++i)
#pragma unroll
      for (int j = 0; j < 4; ++j) acc[i][j] = mfma16(af[i], bfr[j], acc[i][j]);
  }
  float* op = part + ((size_t)lc * 64 + bh) * 4096;
#pragma unroll
  for (int i = 0; i < 4; ++i)
#pragma unroll
    for (int j = 0; j < 4; ++j)
#pragma unroll
      for (int r = 0; r < 4; ++r) {
        int d = i * 16 + lhi * 4 + r, v = j * 16 + llo;
        op[d * 64 + v] = acc[i][j][r];
      }
  // ksum partial: reduce across lhi (lanes ll, ll^16, ll^32)
  float* pks = part_ks + ((size_t)lc * 64 + bh) * 64;
#pragma unroll
  for (int i = 0; i < 4; ++i) {
    float s = ks[i];
    s += __shfl_xor(s, 16);
    s += __shfl_xor(s, 32);
    if (lhi == 0) pks[i * 16 + llo] = s;
  }
}

__global__ void kv_red_k(const float* __restrict__ part, float* __restrict__ kv) {
  const int i = blockIdx.x * blockDim.x + threadIdx.x;  // 0..262143
  float s = 0.f;
#pragma unroll
  for (int lc = 0; lc < 8; ++lc) s += part[(size_t)lc * 262144 + i];
  kv[i] = s;
}

__global__ void ksum_red_k(const float* __restrict__ part_ks, float* __restrict__ ksum) {
  const int i = blockIdx.x * blockDim.x + threadIdx.x;  // 0..4095
  float s = 0.f;
#pragma unroll
  for (int lc = 0; lc < 8; ++lc) s += part_ks[(size_t)lc * 4096 + i];
  ksum[i] = s;
}

// ---------------- apply: attn[b][l][h*64+v] = (sum_d Q[l,d]KV[d,v]) * Z[l] ----------------
__global__ __launch_bounds__(256) void apply_k(const __bf16* __restrict__ qt,
                                               const float* __restrict__ kv,
                                               const float* __restrict__ ksum,
                                               __bf16* __restrict__ attn) {
  __shared__ __attribute__((aligned(16))) __bf16 kvT[64 * 68];
  __shared__ float zb[256];
  const int lc = blockIdx.x, bh = blockIdx.y;
  const int b = bh >> 3, h = bh & 7;
  const int tid = threadIdx.x;
  const float* kvp = kv + (size_t)bh * 4096;
  for (int i = tid; i < 4096; i += 256) {
    int d = i >> 6, v = i & 63;
    kvT[v * 68 + d] = (__bf16)kvp[i];
  }
  const int l = lc * 256 + tid;
  const __bf16* qp = qt + ((size_t)b * LLEN + l) * CCH + h * 64;
  const float* ksp = ksum + bh * 64;
  float s = 0.f;
#pragma unroll
  for (int d8 = 0; d8 < 64; d8 += 8) {
    bf16x8 qv = *(const bf16x8*)(qp + d8);
#pragma unroll
    for (int i = 0; i < 8; ++i) s += (float)qv[i] * ksp[d8 + i];
  }
  zb[tid] = 1.0f / (s + 1e-6f);
  __syncthreads();

  const int ll = tid & 63, w = tid >> 6, lhi = ll >> 4, llo = ll & 15;
  f32x4 acc[4][4];
#pragma unroll
  for (int i = 0; i < 4; ++i)
#pragma unroll
    for (int j = 0; j < 4; ++j) acc[i][j] = (f32x4){0.f, 0.f, 0.f, 0.f};
  const __bf16* qbase = qt + ((size_t)b * LLEN + lc * 256 + w * 64) * CCH + h * 64;
#pragma unroll
  for (int kt = 0; kt < 2; ++kt) {
    const int k8 = kt * 32 + lhi * 8;
    bf16x8 af[4], bfr[4];
#pragma unroll
    for (int i = 0; i < 4; ++i)
      af[i] = *(const bf16x8*)(qbase + (size_t)(i * 16 + llo) * CCH + k8);
#pragma unroll
    for (int j = 0; j < 4; ++j) {
      const __bf16* pb = kvT + (j * 16 + llo) * 68 + k8;
      ((bf16x4*)&bfr[j])[0] = *(const bf16x4*)pb;
      ((bf16x4*)&bfr[j])[1] = *(const bf16x4*)(pb + 4);
    }
#pragma unroll
    for (int i = 0; i < 4; ++i)
#pragma unroll
      for (int j = 0; j < 4; ++j) acc[i][j] = mfma16(af[i], bfr[j], acc[i][j]);
  }
  __bf16* ap = attn + ((size_t)b * LLEN + lc * 256) * CCH + h * 64;
#pragma unroll
  for (int i = 0; i < 4; ++i)
#pragma unroll
    for (int j = 0; j < 4; ++j)
#pragma unroll
      for (int r = 0; r < 4; ++r) {
        int ml = w * 64 + i * 16 + lhi * 4 + r;
        int v = j * 16 + llo;
        ap[(size_t)ml * CCH + v] = (__bf16)(acc[i][j][r] * zb[ml]);
      }
}

extern "C" void kernel_launch(void* const* d_in, const int* in_sizes, int n_in,
                              void* d_out, int out_size, void* d_ws, size_t ws_size,
                              hipStream_t stream) {
  const float* x  = (const float*)d_in[0];
  const float* wq = (const float*)d_in[1];
  const float* bq = (const float*)d_in[2];
  const float* wk = (const float*)d_in[3];
  const float* bk = (const float*)d_in[4];
  const float* wv = (const float*)d_in[5];
  const float* bv = (const float*)d_in[6];
  const float* wo = (const float*)d_in[7];
  const float* bo = (const float*)d_in[8];
  float* out = (float*)d_out;

  char* p = (char*)d_ws;
  __bf16* xt    = (__bf16*)p; p += (size_t)BATCH * LLEN * CCH * 2;  // 32MB (reused as attn)
  __bf16* qt    = (__bf16*)p; p += (size_t)BATCH * LLEN * CCH * 2;  // 32MB
  __bf16* kcm   = (__bf16*)p; p += (size_t)BATCH * CCH * LLEN * 2;  // 32MB
  __bf16* vcm   = (__bf16*)p; p += (size_t)BATCH * CCH * LLEN * 2;  // 32MB
  __bf16* wqkvb = (__bf16*)p; p += (size_t)M1 * CCH * 2;
  __bf16* wob   = (__bf16*)p; p += (size_t)CCH * CCH * 2;
  float*  biasq = (float*)p;  p += (size_t)M1 * 4;
  float*  ksum  = (float*)p;  p += (size_t)BATCH * CCH * 4;
  float*  part  = (float*)p;  p += (size_t)8 * 64 * HD * HD * 4;    // 8MB
  float*  kvb   = (float*)p;  p += (size_t)64 * HD * HD * 4;        // 1MB
  float*  pks   = (float*)p;  p += (size_t)8 * 64 * 64 * 4;         // 128KB
  __bf16* attn  = xt;

  pack_w<<<1024, 256, 0, stream>>>(wq, wk, wv, wo, bq, bk, bv, wqkvb, wob, biasq);
  transpose_x<<<dim3(64, 8, BATCH), 256, 0, stream>>>(x, xt);
  gemm_k<0><<<dim3(32, 12, BATCH), 256, 0, stream>>>(wqkvb, xt, biasq, qt, kcm, vcm, nullptr);
  kv_part_k<<<dim3(8, 64), 64, 0, stream>>>(kcm, vcm, part, pks);
  kv_red_k<<<1024, 256, 0, stream>>>(part, kvb);
  ksum_red_k<<<16, 256, 0, stream>>>(pks, ksum);
  apply_k<<<dim3(16, 64), 256, 0, stream>>>(qt, kvb, ksum, attn);
  gemm_k<1><<<dim3(32, 4, BATCH), 256, 0, stream>>>(wob, attn, bo, nullptr, nullptr, nullptr, out);
}

// Round 3
// 170.230 us; speedup vs baseline: 1.1031x; 1.0158x over previous
//
#include <hip/hip_runtime.h>
#include <hip/hip_bf16.h>
#include <stdint.h>

#define BATCH 8
#define CCH   512
#define NHD   8
#define HD    64
#define LLEN  4096
#define M1    1536

typedef __bf16 bf16x8 __attribute__((ext_vector_type(8)));
typedef __bf16 bf16x4 __attribute__((ext_vector_type(4)));
typedef float  f32x4  __attribute__((ext_vector_type(4)));

__device__ __forceinline__ f32x4 mfma16(bf16x8 a, bf16x8 b, f32x4 c) {
  return __builtin_amdgcn_mfma_f32_16x16x32_bf16(a, b, c, 0, 0, 0);
}

// async global->LDS, 16B per lane. LDS dest is wave-uniform base + lane*16.
__device__ __forceinline__ void gload_lds16(const void* g, void* l) {
  __builtin_amdgcn_global_load_lds(
      (const __attribute__((address_space(1))) uint32_t*)(uintptr_t)g,
      (__attribute__((address_space(3))) uint32_t*)(uintptr_t)l,
      16, 0, 0);
}

// ---------------- pack weights/biases to bf16 ----------------
__global__ void pack_w(const float* __restrict__ wq, const float* __restrict__ wk,
                       const float* __restrict__ wv, const float* __restrict__ wo,
                       const float* __restrict__ bq, const float* __restrict__ bk,
                       const float* __restrict__ bv,
                       __bf16* __restrict__ wqkvb, __bf16* __restrict__ wob,
                       float* __restrict__ biasq) {
  const int n = M1 * CCH + CCH * CCH + M1;
  for (int i = blockIdx.x * blockDim.x + threadIdx.x; i < n; i += gridDim.x * blockDim.x) {
    if (i < M1 * CCH) {
      int r = i >> 9, c = i & 511;
      float v = (r < 512) ? wq[r * 512 + c]
              : (r < 1024) ? wk[(r - 512) * 512 + c]
                           : wv[(r - 1024) * 512 + c];
      wqkvb[i] = (__bf16)v;
    } else if (i < M1 * CCH + CCH * CCH) {
      int j = i - M1 * CCH;
      wob[j] = (__bf16)wo[j];
    } else {
      int j = i - M1 * CCH - CCH * CCH;
      biasq[j] = (j < 512) ? bq[j] : (j < 1024) ? bk[j - 512] : bv[j - 1024];
    }
  }
}

// ---------------- x [b][C][L] fp32 -> xt [b][L][C] bf16 (64x64 tiles) ----------------
__global__ __launch_bounds__(256) void transpose_x(const float* __restrict__ x,
                                                   __bf16* __restrict__ xt) {
  __shared__ float tile[64][65];
  const int b = blockIdx.z, c0 = blockIdx.y * 64, l0 = blockIdx.x * 64;
  const int t = threadIdx.x;
  const int lq = (t & 15) * 4, cr = t >> 4;
  const float* xp = x + ((size_t)b * CCH + c0) * LLEN + l0;
#pragma unroll
  for (int q = 0; q < 4; ++q) {
    const int c = cr + q * 16;
    float4 v = *(const float4*)(xp + (size_t)c * LLEN + lq);
    tile[c][lq + 0] = v.x;
    tile[c][lq + 1] = v.y;
    tile[c][lq + 2] = v.z;
    tile[c][lq + 3] = v.w;
  }
  __syncthreads();
  __bf16* xo = xt + ((size_t)b * LLEN + l0) * CCH + c0;
  const int c4 = (t & 15) * 4, lr = t >> 4;
#pragma unroll
  for (int p = 0; p < 4; ++p) {
    const int l = lr + p * 16;
    bf16x4 o;
#pragma unroll
    for (int i = 0; i < 4; ++i) o[i] = (__bf16)tile[c4 + i][l];
    *(bf16x4*)(xo + (size_t)l * CCH + c4) = o;
  }
}

// ================= 256x256 phased GEMM (BK=32, 8 waves, triple-buffered LDS) ========
// D[m][n] = A[M][512] * B[b][n][k] (B rows k-major).
// EPI 0: QKV epilogue (bias + elu+1 on Q/K; write qt [b][l][c], kcm/vcm [b][c][l])
// EPI 1: output epilogue (bias; write fp32 out [b][c][l])
//
// LDS layout per tile per matrix: 128 lines x 128B; line r2 holds rows 2*r2, 2*r2+1.
// 16B chunk c at (row R, k-chunk kc) stored at chunk ((R&1)*4+kc) ^ (r2&7)  (XOR swizzle,
// involution). global_load_lds writes LINEAR dest; source address inverse-swizzled.
#define STAGE_A(kt, base)                                                    \
  {                                                                          \
    _Pragma("unroll") for (int p = 0; p < 2; ++p)                            \
        gload_lds16(Ag + (size_t)sR[p] * CCH + (kt) * 32 + sK[p],            \
                    lds + (base) + sDst[p]);                                 \
  }
#define STAGE_B(kt, base)                                                    \
  {                                                                          \
    _Pragma("unroll") for (int p = 0; p < 2; ++p)                            \
        gload_lds16(Bg + (size_t)sR[p] * CCH + (kt) * 32 + sK[p],            \
                    lds + (base) + 8192 + sDst[p]);                          \
  }

template <int EPI>
__global__ __launch_bounds__(512, 2) void gemm256(
    const __bf16* __restrict__ A, const __bf16* __restrict__ Bm,
    const float* __restrict__ bias,
    __bf16* __restrict__ qt, __bf16* __restrict__ kcm, __bf16* __restrict__ vcm,
    float* __restrict__ out) {
  __shared__ __attribute__((aligned(16))) __bf16 lds[3 * 16384];  // 96KB: 3 x (A 16KB + B 16KB)
  const int b  = blockIdx.z;
  const int n0 = blockIdx.x * 256;
  const int m0 = blockIdx.y * 256;
  const int tid = threadIdx.x;
  const int ll = tid & 63, w = tid >> 6;  // 8 waves
  const int wr = w >> 2, wc = w & 3;      // 2M x 4N
  const int lhi = ll >> 4, llo = ll & 15;

  // swizzled read offsets (elements within one matrix tile buffer)
  int aoff[8], boff[4];
#pragma unroll
  for (int m = 0; m < 8; ++m) {
    int R = wr * 128 + m * 16 + llo;
    aoff[m] = ((R >> 1) << 6) + (((((R & 1) << 2) | lhi) ^ ((R >> 1) & 7)) << 3);
  }
#pragma unroll
  for (int n = 0; n < 4; ++n) {
    int R = wc * 64 + n * 16 + llo;
    boff[n] = ((R >> 1) << 6) + (((((R & 1) << 2) | lhi) ^ ((R >> 1) & 7)) << 3) + 8192;
  }

  // staging decode: linear LDS slot -> (global row, k-chunk) via inverse swizzle
  int sR[2], sK[2], sDst[2];
#pragma unroll
  for (int p = 0; p < 2; ++p) {
    int idx = p * 512 + tid;                 // 16B slot index, 0..1023
    int r2 = idx >> 3, c7u = (idx & 7) ^ (r2 & 7);
    sR[p]   = (r2 << 1) | (c7u >> 2);
    sK[p]   = (c7u & 3) << 3;
    sDst[p] = idx * 8;                       // element offset
  }
  const __bf16* Ag = A + (size_t)m0 * CCH;
  const __bf16* Bg = Bm + ((size_t)b * LLEN + n0) * CCH;

  // prologue: stage tiles 0,1; ensure tile0 resident, keep tile1 in flight
  STAGE_A(0, 0) STAGE_B(0, 0)
  STAGE_A(1, 16384) STAGE_B(1, 16384)
  asm volatile("s_waitcnt vmcnt(4)" ::: "memory");
  __builtin_amdgcn_s_barrier();

  f32x4 acc[8][4] = {};
  int bi = 0;
  for (int t = 0; t < 16; ++t) {
    const int abase = bi * 16384;
    const int sb = ((bi == 0) ? 2 : bi - 1) * 16384;  // (t+2)%3
    bf16x8 af[4], bfr[4];
    // ---- phase 0: m-frags 0..3 ----
#pragma unroll
    for (int i = 0; i < 4; ++i) af[i] = *(const bf16x8*)(lds + abase + aoff[i]);
#pragma unroll
    for (int j = 0; j < 4; ++j) bfr[j] = *(const bf16x8*)(lds + abase + boff[j]);
    if (t + 2 < 16) STAGE_A(t + 2, sb)
    __builtin_amdgcn_s_barrier();
    asm volatile("s_waitcnt lgkmcnt(0)" ::: "memory");
    __builtin_amdgcn_sched_barrier(0);
    __builtin_amdgcn_s_setprio(1);
#pragma unroll
    for (int i = 0; i < 4; ++i)
#pragma unroll
      for (int j = 0; j < 4; ++j) acc[i][j] = mfma16(af[i], bfr[j], acc[i][j]);
    __builtin_amdgcn_s_setprio(0);
    __builtin_amdgcn_s_barrier();
    // ---- phase 1: m-frags 4..7 (B frags reused) ----
#pragma unroll
    for (int i = 0; i < 4; ++i) af[i] = *(const bf16x8*)(lds + abase + aoff[4 + i]);
    if (t + 2 < 16) {
      STAGE_B(t + 2, sb)
      asm volatile("s_waitcnt vmcnt(4)" ::: "memory");  // tile t+1 fully resident
    } else {
      asm volatile("s_waitcnt vmcnt(0)" ::: "memory");
    }
    __builtin_amdgcn_s_barrier();
    asm volatile("s_waitcnt lgkmcnt(0)" ::: "memory");
    __builtin_amdgcn_sched_barrier(0);
    __builtin_amdgcn_s_setprio(1);
#pragma unroll
    for (int i = 0; i < 4; ++i)
#pragma unroll
      for (int j = 0; j < 4; ++j) acc[4 + i][j] = mfma16(af[i], bfr[j], acc[4 + i][j]);
    __builtin_amdgcn_s_setprio(0);
    __builtin_amdgcn_s_barrier();
    bi = (bi == 2) ? 0 : bi + 1;
  }

  // epilogue
#pragma unroll
  for (int i = 0; i < 8; ++i) {
    const int o0 = m0 + wr * 128 + i * 16 + lhi * 4;
#pragma unroll
    for (int j = 0; j < 4; ++j) {
      const int col = n0 + wc * 64 + j * 16 + llo;
      if (EPI == 0) {
        if (m0 < 512) {
          bf16x4 pk;
#pragma unroll
          for (int r = 0; r < 4; ++r) {
            float tv = acc[i][j][r] + bias[o0 + r];
            tv = tv > 0.f ? tv + 1.f : __expf(tv);
            pk[r] = (__bf16)tv;
          }
          *(bf16x4*)(qt + ((size_t)b * LLEN + col) * CCH + o0) = pk;
        } else if (m0 < 1024) {
#pragma unroll
          for (int r = 0; r < 4; ++r) {
            float tv = acc[i][j][r] + bias[o0 + r];
            tv = tv > 0.f ? tv + 1.f : __expf(tv);
            kcm[((size_t)b * CCH + (o0 - 512 + r)) * LLEN + col] = (__bf16)tv;
          }
        } else {
#pragma unroll
          for (int r = 0; r < 4; ++r)
            vcm[((size_t)b * CCH + (o0 - 1024 + r)) * LLEN + col] =
                (__bf16)(acc[i][j][r] + bias[o0 + r]);
        }
      } else {
#pragma unroll
        for (int r = 0; r < 4; ++r)
          out[((size_t)b * CCH + o0 + r) * LLEN + col] = acc[i][j][r] + bias[o0 + r];
      }
    }
  }
}

// ---------------- KV partials + fused Ksum partials ----------------
__global__ __launch_bounds__(64) void kv_part_k(const __bf16* __restrict__ kcm,
                                                const __bf16* __restrict__ vcm,
                                                float* __restrict__ part,
                                                float* __restrict__ part_ks) {
  const int lc = blockIdx.x, bh = blockIdx.y;
  const int b = bh >> 3, h = bh & 7;
  const int ll = threadIdx.x, lhi = ll >> 4, llo = ll & 15;
  const __bf16* Kp = kcm + ((size_t)b * CCH + h * 64) * LLEN;
  const __bf16* Vp = vcm + ((size_t)b * CCH + h * 64) * LLEN;
  f32x4 acc[4][4];
#pragma unroll
  for (int i = 0; i < 4; ++i)
#pragma unroll
    for (int j = 0; j < 4; ++j) acc[i][j] = (f32x4){0.f, 0.f, 0.f, 0.f};
  float ks[4] = {0.f, 0.f, 0.f, 0.f};
  const int base = lc * 512 + lhi * 8;
  for (int kt = 0; kt < 16; ++kt) {
    const int k0 = base + kt * 32;
    bf16x8 af[4], bfr[4];
#pragma unroll
    for (int i = 0; i < 4; ++i) af[i]  = *(const bf16x8*)(Kp + (size_t)(i * 16 + llo) * LLEN + k0);
#pragma unroll
    for (int i = 0; i < 4; ++i) bfr[i] = *(const bf16x8*)(Vp + (size_t)(i * 16 + llo) * LLEN + k0);
#pragma unroll
    for (int i = 0; i < 4; ++i)
#pragma unroll
      for (int r = 0; r < 8; ++r) ks[i] += (float)af[i][r];
#pragma unroll
    for (int i = 0; i < 4; ++i)
#pragma unroll
      for (int j = 0; j < 4; ++j) acc[i][j] = mfma16(af[i], bfr[j], acc[i][j]);
  }
  float* op = part + ((size_t)lc * 64 + bh) * 4096;
#pragma unroll
  for (int i = 0; i < 4; ++i)
#pragma unroll
    for (int j = 0; j < 4; ++j)
#pragma unroll
      for (int r = 0; r < 4; ++r) {
        int d = i * 16 + lhi * 4 + r, v = j * 16 + llo;
        op[d * 64 + v] = acc[i][j][r];
      }
  float* pks = part_ks + ((size_t)lc * 64 + bh) * 64;
#pragma unroll
  for (int i = 0; i < 4; ++i) {
    float s = ks[i];
    s += __shfl_xor(s, 16);
    s += __shfl_xor(s, 32);
    if (lhi == 0) pks[i * 16 + llo] = s;
  }
}

__global__ void kv_red_k(const float* __restrict__ part, float* __restrict__ kv) {
  const int i = blockIdx.x * blockDim.x + threadIdx.x;
  float s = 0.f;
#pragma unroll
  for (int lc = 0; lc < 8; ++lc) s += part[(size_t)lc * 262144 + i];
  kv[i] = s;
}

__global__ void ksum_red_k(const float* __restrict__ part_ks, float* __restrict__ ksum) {
  const int i = blockIdx.x * blockDim.x + threadIdx.x;
  float s = 0.f;
#pragma unroll
  for (int lc = 0; lc < 8; ++lc) s += part_ks[(size_t)lc * 4096 + i];
  ksum[i] = s;
}

// ---------------- apply: attn[b][l][h*64+v] = (sum_d Q[l,d]KV[d,v]) * Z[l] ----------------
__global__ __launch_bounds__(256) void apply_k(const __bf16* __restrict__ qt,
                                               const float* __restrict__ kv,
                                               const float* __restrict__ ksum,
                                               __bf16* __restrict__ attn) {
  __shared__ __attribute__((aligned(16))) __bf16 kvT[64 * 68];
  __shared__ float zb[256];
  const int lc = blockIdx.x, bh = blockIdx.y;
  const int b = bh >> 3, h = bh & 7;
  const int tid = threadIdx.x;
  const float* kvp = kv + (size_t)bh * 4096;
  for (int i = tid; i < 4096; i += 256) {
    int d = i >> 6, v = i & 63;
    kvT[v * 68 + d] = (__bf16)kvp[i];
  }
  const int l = lc * 256 + tid;
  const __bf16* qp = qt + ((size_t)b * LLEN + l) * CCH + h * 64;
  const float* ksp = ksum + bh * 64;
  float s = 0.f;
#pragma unroll
  for (int d8 = 0; d8 < 64; d8 += 8) {
    bf16x8 qv = *(const bf16x8*)(qp + d8);
#pragma unroll
    for (int i = 0; i < 8; ++i) s += (float)qv[i] * ksp[d8 + i];
  }
  zb[tid] = 1.0f / (s + 1e-6f);
  __syncthreads();

  const int ll = tid & 63, w = tid >> 6, lhi = ll >> 4, llo = ll & 15;
  f32x4 acc[4][4];
#pragma unroll
  for (int i = 0; i < 4; ++i)
#pragma unroll
    for (int j = 0; j < 4; ++j) acc[i][j] = (f32x4){0.f, 0.f, 0.f, 0.f};
  const __bf16* qbase = qt + ((size_t)b * LLEN + lc * 256 + w * 64) * CCH + h * 64;
#pragma unroll
  for (int kt = 0; kt < 2; ++kt) {
    const int k8 = kt * 32 + lhi * 8;
    bf16x8 af[4], bfr[4];
#pragma unroll
    for (int i = 0; i < 4; ++i)
      af[i] = *(const bf16x8*)(qbase + (size_t)(i * 16 + llo) * CCH + k8);
#pragma unroll
    for (int j = 0; j < 4; ++j) {
      const __bf16* pb = kvT + (j * 16 + llo) * 68 + k8;
      ((bf16x4*)&bfr[j])[0] = *(const bf16x4*)pb;
      ((bf16x4*)&bfr[j])[1] = *(const bf16x4*)(pb + 4);
    }
#pragma unroll
    for (int i = 0; i < 4; ++i)
#pragma unroll
      for (int j = 0; j < 4; ++j) acc[i][j] = mfma16(af[i], bfr[j], acc[i][j]);
  }
  __bf16* ap = attn + ((size_t)b * LLEN + lc * 256) * CCH + h * 64;
#pragma unroll
  for (int i = 0; i < 4; ++i)
#pragma unroll
    for (int j = 0; j < 4; ++j)
#pragma unroll
      for (int r = 0; r < 4; ++r) {
        int ml = w * 64 + i * 16 + lhi * 4 + r;
        int v = j * 16 + llo;
        ap[(size_t)ml * CCH + v] = (__bf16)(acc[i][j][r] * zb[ml]);
      }
}

extern "C" void kernel_launch(void* const* d_in, const int* in_sizes, int n_in,
                              void* d_out, int out_size, void* d_ws, size_t ws_size,
                              hipStream_t stream) {
  const float* x  = (const float*)d_in[0];
  const float* wq = (const float*)d_in[1];
  const float* bq = (const float*)d_in[2];
  const float* wk = (const float*)d_in[3];
  const float* bk = (const float*)d_in[4];
  const float* wv = (const float*)d_in[5];
  const float* bv = (const float*)d_in[6];
  const float* wo = (const float*)d_in[7];
  const float* bo = (const float*)d_in[8];
  float* out = (float*)d_out;

  char* p = (char*)d_ws;
  __bf16* xt    = (__bf16*)p; p += (size_t)BATCH * LLEN * CCH * 2;  // 32MB (reused as attn)
  __bf16* qt    = (__bf16*)p; p += (size_t)BATCH * LLEN * CCH * 2;  // 32MB
  __bf16* kcm   = (__bf16*)p; p += (size_t)BATCH * CCH * LLEN * 2;  // 32MB
  __bf16* vcm   = (__bf16*)p; p += (size_t)BATCH * CCH * LLEN * 2;  // 32MB
  __bf16* wqkvb = (__bf16*)p; p += (size_t)M1 * CCH * 2;
  __bf16* wob   = (__bf16*)p; p += (size_t)CCH * CCH * 2;
  float*  biasq = (float*)p;  p += (size_t)M1 * 4;
  float*  ksum  = (float*)p;  p += (size_t)BATCH * CCH * 4;
  float*  part  = (float*)p;  p += (size_t)8 * 64 * HD * HD * 4;    // 8MB
  float*  kvb   = (float*)p;  p += (size_t)64 * HD * HD * 4;        // 1MB
  float*  pks   = (float*)p;  p += (size_t)8 * 64 * 64 * 4;         // 128KB
  __bf16* attn  = xt;

  pack_w<<<1024, 256, 0, stream>>>(wq, wk, wv, wo, bq, bk, bv, wqkvb, wob, biasq);
  transpose_x<<<dim3(64, 8, BATCH), 256, 0, stream>>>(x, xt);
  gemm256<0><<<dim3(16, 6, BATCH), 512, 0, stream>>>(wqkvb, xt, biasq, qt, kcm, vcm, nullptr);
  kv_part_k<<<dim3(8, 64), 64, 0, stream>>>(kcm, vcm, part, pks);
  kv_red_k<<<1024, 256, 0, stream>>>(part, kvb);
  ksum_red_k<<<16, 256, 0, stream>>>(pks, ksum);
  apply_k<<<dim3(16, 64), 256, 0, stream>>>(qt, kvb, ksum, attn);
  gemm256<1><<<dim3(16, 2, BATCH), 512, 0, stream>>>(wob, attn, bo, nullptr, nullptr, nullptr, out);
}

// Round 4
// 170.191 us; speedup vs baseline: 1.1034x; 1.0002x over previous
//
#include <hip/hip_runtime.h>
#include <hip/hip_bf16.h>
#include <stdint.h>

#define BATCH 8
#define CCH   512
#define NHD   8
#define HD    64
#define LLEN  4096
#define M1    1536

typedef __bf16 bf16x8 __attribute__((ext_vector_type(8)));
typedef __bf16 bf16x4 __attribute__((ext_vector_type(4)));
typedef float  f32x4  __attribute__((ext_vector_type(4)));

__device__ __forceinline__ f32x4 mfma16(bf16x8 a, bf16x8 b, f32x4 c) {
  return __builtin_amdgcn_mfma_f32_16x16x32_bf16(a, b, c, 0, 0, 0);
}

// async global->LDS, 16B per lane. LDS dest is wave-uniform base + lane*16.
__device__ __forceinline__ void gload_lds16(const void* g, void* l) {
  __builtin_amdgcn_global_load_lds(
      (const __attribute__((address_space(1))) uint32_t*)(uintptr_t)g,
      (__attribute__((address_space(3))) uint32_t*)(uintptr_t)l,
      16, 0, 0);
}

// ---------------- pack weights/biases to bf16 ----------------
__global__ void pack_w(const float* __restrict__ wq, const float* __restrict__ wk,
                       const float* __restrict__ wv, const float* __restrict__ wo,
                       const float* __restrict__ bq, const float* __restrict__ bk,
                       const float* __restrict__ bv,
                       __bf16* __restrict__ wqkvb, __bf16* __restrict__ wob,
                       float* __restrict__ biasq) {
  const int n = M1 * CCH + CCH * CCH + M1;
  for (int i = blockIdx.x * blockDim.x + threadIdx.x; i < n; i += gridDim.x * blockDim.x) {
    if (i < M1 * CCH) {
      int r = i >> 9, c = i & 511;
      float v = (r < 512) ? wq[r * 512 + c]
              : (r < 1024) ? wk[(r - 512) * 512 + c]
                           : wv[(r - 1024) * 512 + c];
      wqkvb[i] = (__bf16)v;
    } else if (i < M1 * CCH + CCH * CCH) {
      int j = i - M1 * CCH;
      wob[j] = (__bf16)wo[j];
    } else {
      int j = i - M1 * CCH - CCH * CCH;
      biasq[j] = (j < 512) ? bq[j] : (j < 1024) ? bk[j - 512] : bv[j - 1024];
    }
  }
}

// ---------------- x [b][C][L] fp32 -> xt [b][L][C] bf16 (64x64 tiles) ----------------
__global__ __launch_bounds__(256) void transpose_x(const float* __restrict__ x,
                                                   __bf16* __restrict__ xt) {
  __shared__ float tile[64][65];
  const int b = blockIdx.z, c0 = blockIdx.y * 64, l0 = blockIdx.x * 64;
  const int t = threadIdx.x;
  const int lq = (t & 15) * 4, cr = t >> 4;
  const float* xp = x + ((size_t)b * CCH + c0) * LLEN + l0;
#pragma unroll
  for (int q = 0; q < 4; ++q) {
    const int c = cr + q * 16;
    float4 v = *(const float4*)(xp + (size_t)c * LLEN + lq);
    tile[c][lq + 0] = v.x;
    tile[c][lq + 1] = v.y;
    tile[c][lq + 2] = v.z;
    tile[c][lq + 3] = v.w;
  }
  __syncthreads();
  __bf16* xo = xt + ((size_t)b * LLEN + l0) * CCH + c0;
  const int c4 = (t & 15) * 4, lr = t >> 4;
#pragma unroll
  for (int p = 0; p < 4; ++p) {
    const int l = lr + p * 16;
    bf16x4 o;
#pragma unroll
    for (int i = 0; i < 4; ++i) o[i] = (__bf16)tile[c4 + i][l];
    *(bf16x4*)(xo + (size_t)l * CCH + c4) = o;
  }
}

// ============ 256x256 pipelined GEMM: BK=32, 16 K-tiles, 8 waves, 3x32KB LDS ========
// Per tile: [barrier][stage t+2][vmcnt(4)][barrier][issue reads t+1][lgkmcnt(12)]
//           [32 MFMA on tile t's frags]  -- LDS read stream overlaps MFMA stream.
// Swizzle (proven 0-conflict r3): 128B line = 2 rows; chunk slot = ((R&1)*4+c)^(line&7).
#define STAGE4(tt)                                                           \
  {                                                                          \
    const int tK = (tt) * 32;                                                \
    const int bs = ((tt) % 3) * 16384;                                       \
    gload_lds16(Ag + sOff + tK,         lds + bs + tid * 8);                 \
    gload_lds16(Ag + sOff + 65536 + tK, lds + bs + 4096 + tid * 8);          \
    gload_lds16(Bg + sOff + tK,         lds + bs + 8192 + tid * 8);          \
    gload_lds16(Bg + sOff + 65536 + tK, lds + bs + 12288 + tid * 8);         \
  }
#define READS12(tt)                                                          \
  {                                                                          \
    const int rb = ((tt) % 3) * 16384;                                       \
    const int s = (tt) & 1;                                                  \
    _Pragma("unroll") for (int m = 0; m < 8; ++m)                            \
        aS[s][m] = *(const bf16x8*)(lds + rb + aLane + m * 512);             \
    _Pragma("unroll") for (int n = 0; n < 4; ++n)                            \
        bS[s][n] = *(const bf16x8*)(lds + rb + bLane + n * 512);             \
  }

template <int EPI>
__global__ __launch_bounds__(512, 2) void gemm256(
    const __bf16* __restrict__ A, const __bf16* __restrict__ Bm,
    const float* __restrict__ bias,
    __bf16* __restrict__ qt, __bf16* __restrict__ kcm, __bf16* __restrict__ vcm,
    float* __restrict__ out) {
  __shared__ __attribute__((aligned(16))) __bf16 lds[3 * 16384];  // 96KB
  const int b  = blockIdx.z;
  const int n0 = blockIdx.x * 256;
  const int m0 = blockIdx.y * 256;
  const int tid = threadIdx.x;
  const int ll = tid & 63, w = tid >> 6;  // 8 waves
  const int wr = w >> 2, wc = w & 3;      // 2M x 4N
  const int lhi = ll >> 4, llo = ll & 15;

  // fragment-read lane offsets (elements), swizzled; frag m adds m*512, n adds n*512
  const int Ra = wr * 128 + llo;
  const int aLane = ((Ra >> 1) << 6) + (((((Ra & 1) << 2) | lhi) ^ ((Ra >> 1) & 7)) << 3);
  const int Rb = wc * 64 + llo;
  const int bLane = 8192 + ((Rb >> 1) << 6) + (((((Rb & 1) << 2) | lhi) ^ ((Rb >> 1) & 7)) << 3);

  // staging source (inverse swizzle); p=1 adds 128*CCH=65536, dest adds 4096 elems
  const int r2s = tid >> 3, c7u = (tid & 7) ^ (r2s & 7);
  const int sRow = (r2s << 1) | (c7u >> 2);
  const int sOff = sRow * CCH + ((c7u & 3) << 3);

  const __bf16* Ag = A + (size_t)m0 * CCH;
  const __bf16* Bg = Bm + ((size_t)b * LLEN + n0) * CCH;

  bf16x8 aS[2][8], bS[2][4];
  f32x4 acc[8][4] = {};

  // prologue: stage tiles 0,1; tile0 resident; issue tile0 frag reads
  STAGE4(0)
  STAGE4(1)
  asm volatile("s_waitcnt vmcnt(4)" ::: "memory");
  asm volatile("s_barrier" ::: "memory");
  READS12(0)

#pragma unroll
  for (int t = 0; t < 16; ++t) {
    asm volatile("s_barrier" ::: "memory");  // A: prior-buffer readers all done
    if (t < 14) STAGE4(t + 2)
    if (t < 14) asm volatile("s_waitcnt vmcnt(4)" ::: "memory");
    else        asm volatile("s_waitcnt vmcnt(0)" ::: "memory");
    asm volatile("s_barrier" ::: "memory");  // B: tile t+1 resident for ALL waves
    if (t < 15) READS12(t + 1)
    if (t < 15) asm volatile("s_waitcnt lgkmcnt(12)" ::: "memory");
    else        asm volatile("s_waitcnt lgkmcnt(0)" ::: "memory");
    __builtin_amdgcn_sched_barrier(0);
    __builtin_amdgcn_s_setprio(1);
    {
      const int s = t & 1;
#pragma unroll
      for (int m = 0; m < 8; ++m)
#pragma unroll
        for (int n = 0; n < 4; ++n) acc[m][n] = mfma16(aS[s][m], bS[s][n], acc[m][n]);
    }
    __builtin_amdgcn_s_setprio(0);
  }

  // epilogue
#pragma unroll
  for (int i = 0; i < 8; ++i) {
    const int o0 = m0 + wr * 128 + i * 16 + lhi * 4;
#pragma unroll
    for (int j = 0; j < 4; ++j) {
      const int col = n0 + wc * 64 + j * 16 + llo;
      if (EPI == 0) {
        if (m0 < 512) {
          bf16x4 pk;
#pragma unroll
          for (int r = 0; r < 4; ++r) {
            float tv = acc[i][j][r] + bias[o0 + r];
            tv = tv > 0.f ? tv + 1.f : __expf(tv);
            pk[r] = (__bf16)tv;
          }
          *(bf16x4*)(qt + ((size_t)b * LLEN + col) * CCH + o0) = pk;
        } else if (m0 < 1024) {
#pragma unroll
          for (int r = 0; r < 4; ++r) {
            float tv = acc[i][j][r] + bias[o0 + r];
            tv = tv > 0.f ? tv + 1.f : __expf(tv);
            kcm[((size_t)b * CCH + (o0 - 512 + r)) * LLEN + col] = (__bf16)tv;
          }
        } else {
#pragma unroll
          for (int r = 0; r < 4; ++r)
            vcm[((size_t)b * CCH + (o0 - 1024 + r)) * LLEN + col] =
                (__bf16)(acc[i][j][r] + bias[o0 + r]);
        }
      } else {
#pragma unroll
        for (int r = 0; r < 4; ++r)
          out[((size_t)b * CCH + o0 + r) * LLEN + col] = acc[i][j][r] + bias[o0 + r];
      }
    }
  }
}

// ---------------- KV partials + fused Ksum partials (4 waves, LDS reduce) ----------------
__global__ __launch_bounds__(256) void kv_part_k(const __bf16* __restrict__ kcm,
                                                 const __bf16* __restrict__ vcm,
                                                 float* __restrict__ part,
                                                 float* __restrict__ part_ks) {
  __shared__ float red[8192];      // 32KB: two waves' partials
  __shared__ float ksred[4][64];
  const int lc = blockIdx.x, bh = blockIdx.y;
  const int b = bh >> 3, h = bh & 7;
  const int tid = threadIdx.x;
  const int w = tid >> 6, ll = tid & 63, lhi = ll >> 4, llo = ll & 15;
  const __bf16* Kp = kcm + ((size_t)b * CCH + h * 64) * LLEN;
  const __bf16* Vp = vcm + ((size_t)b * CCH + h * 64) * LLEN;
  f32x4 acc[4][4];
#pragma unroll
  for (int i = 0; i < 4; ++i)
#pragma unroll
    for (int j = 0; j < 4; ++j) acc[i][j] = (f32x4){0.f, 0.f, 0.f, 0.f};
  float ks[4] = {0.f, 0.f, 0.f, 0.f};
  const int base = lc * 512 + w * 128 + lhi * 8;
#pragma unroll
  for (int kt = 0; kt < 4; ++kt) {
    const int k0 = base + kt * 32;
    bf16x8 af[4], bfr[4];
#pragma unroll
    for (int i = 0; i < 4; ++i) af[i]  = *(const bf16x8*)(Kp + (size_t)(i * 16 + llo) * LLEN + k0);
#pragma unroll
    for (int i = 0; i < 4; ++i) bfr[i] = *(const bf16x8*)(Vp + (size_t)(i * 16 + llo) * LLEN + k0);
#pragma unroll
    for (int i = 0; i < 4; ++i)
#pragma unroll
      for (int r = 0; r < 8; ++r) ks[i] += (float)af[i][r];
#pragma unroll
    for (int i = 0; i < 4; ++i)
#pragma unroll
      for (int j = 0; j < 4; ++j) acc[i][j] = mfma16(af[i], bfr[j], acc[i][j]);
  }
  // ksum partial per wave (reduce across lhi)
#pragma unroll
  for (int i = 0; i < 4; ++i) {
    float s = ks[i];
    s += __shfl_xor(s, 16);
    s += __shfl_xor(s, 32);
    if (lhi == 0) ksred[w][i * 16 + llo] = s;
  }
  // tree-reduce acc across 4 waves via LDS (frag-layout, f32x4)
  if (w >= 2) {
#pragma unroll
    for (int i = 0; i < 4; ++i)
#pragma unroll
      for (int j = 0; j < 4; ++j)
        *(f32x4*)(red + (((w - 2) * 16 + i * 4 + j) << 8) + ll * 4) = acc[i][j];
  }
  __syncthreads();
  if (w < 2) {
#pragma unroll
    for (int i = 0; i < 4; ++i)
#pragma unroll
      for (int j = 0; j < 4; ++j)
        acc[i][j] += *(const f32x4*)(red + ((w * 16 + i * 4 + j) << 8) + ll * 4);
  }
  // fused ksum reduce (wave 1's lanes 0..63 handle it after first barrier data is ready)
  float ksv = 0.f;
  if (w == 1) ksv = ksred[0][ll] + ksred[1][ll] + ksred[2][ll] + ksred[3][ll];
  __syncthreads();
  if (w == 1) {
#pragma unroll
    for (int i = 0; i < 4; ++i)
#pragma unroll
      for (int j = 0; j < 4; ++j)
        *(f32x4*)(red + ((i * 4 + j) << 8) + ll * 4) = acc[i][j];
    part_ks[((size_t)lc * 64 + bh) * 64 + ll] = ksv;
  }
  __syncthreads();
  if (w == 0) {
    float* op = part + ((size_t)lc * 64 + bh) * 4096;
#pragma unroll
    for (int i = 0; i < 4; ++i)
#pragma unroll
      for (int j = 0; j < 4; ++j) {
        acc[i][j] += *(const f32x4*)(red + ((i * 4 + j) << 8) + ll * 4);
#pragma unroll
        for (int r = 0; r < 4; ++r) {
          int d = i * 16 + lhi * 4 + r, v = j * 16 + llo;
          op[d * 64 + v] = acc[i][j][r];
        }
      }
  }
}

__global__ void kv_red_k(const float* __restrict__ part, float* __restrict__ kv) {
  const int i = blockIdx.x * blockDim.x + threadIdx.x;
  float s = 0.f;
#pragma unroll
  for (int lc = 0; lc < 8; ++lc) s += part[(size_t)lc * 262144 + i];
  kv[i] = s;
}

__global__ void ksum_red_k(const float* __restrict__ part_ks, float* __restrict__ ksum) {
  const int i = blockIdx.x * blockDim.x + threadIdx.x;
  float s = 0.f;
#pragma unroll
  for (int lc = 0; lc < 8; ++lc) s += part_ks[(size_t)lc * 4096 + i];
  ksum[i] = s;
}

// ---------------- apply: attn[b][l][h*64+v] = (sum_d Q[l,d]KV[d,v]) * Z[l] ----------------
__global__ __launch_bounds__(256) void apply_k(const __bf16* __restrict__ qt,
                                               const float* __restrict__ kv,
                                               const float* __restrict__ ksum,
                                               __bf16* __restrict__ attn) {
  __shared__ __attribute__((aligned(16))) __bf16 kvT[64 * 68];
  __shared__ float zb[256];
  const int lc = blockIdx.x, bh = blockIdx.y;
  const int b = bh >> 3, h = bh & 7;
  const int tid = threadIdx.x;
  const float* kvp = kv + (size_t)bh * 4096;
  for (int i = tid; i < 4096; i += 256) {
    int d = i >> 6, v = i & 63;
    kvT[v * 68 + d] = (__bf16)kvp[i];
  }
  const int l = lc * 256 + tid;
  const __bf16* qp = qt + ((size_t)b * LLEN + l) * CCH + h * 64;
  const float* ksp = ksum + bh * 64;
  float s = 0.f;
#pragma unroll
  for (int d8 = 0; d8 < 64; d8 += 8) {
    bf16x8 qv = *(const bf16x8*)(qp + d8);
#pragma unroll
    for (int i = 0; i < 8; ++i) s += (float)qv[i] * ksp[d8 + i];
  }
  zb[tid] = 1.0f / (s + 1e-6f);
  __syncthreads();

  const int ll = tid & 63, w = tid >> 6, lhi = ll >> 4, llo = ll & 15;
  f32x4 acc[4][4];
#pragma unroll
  for (int i = 0; i < 4; ++i)
#pragma unroll
    for (int j = 0; j < 4; ++j) acc[i][j] = (f32x4){0.f, 0.f, 0.f, 0.f};
  const __bf16* qbase = qt + ((size_t)b * LLEN + lc * 256 + w * 64) * CCH + h * 64;
#pragma unroll
  for (int kt = 0; kt < 2; ++kt) {
    const int k8 = kt * 32 + lhi * 8;
    bf16x8 af[4], bfr[4];
#pragma unroll
    for (int i = 0; i < 4; ++i)
      af[i] = *(const bf16x8*)(qbase + (size_t)(i * 16 + llo) * CCH + k8);
#pragma unroll
    for (int j = 0; j < 4; ++j) {
      const __bf16* pb = kvT + (j * 16 + llo) * 68 + k8;
      ((bf16x4*)&bfr[j])[0] = *(const bf16x4*)pb;
      ((bf16x4*)&bfr[j])[1] = *(const bf16x4*)(pb + 4);
    }
#pragma unroll
    for (int i = 0; i < 4; ++i)
#pragma unroll
      for (int j = 0; j < 4; ++j) acc[i][j] = mfma16(af[i], bfr[j], acc[i][j]);
  }
  __bf16* ap = attn + ((size_t)b * LLEN + lc * 256) * CCH + h * 64;
#pragma unroll
  for (int i = 0; i < 4; ++i)
#pragma unroll
    for (int j = 0; j < 4; ++j)
#pragma unroll
      for (int r = 0; r < 4; ++r) {
        int ml = w * 64 + i * 16 + lhi * 4 + r;
        int v = j * 16 + llo;
        ap[(size_t)ml * CCH + v] = (__bf16)(acc[i][j][r] * zb[ml]);
      }
}

extern "C" void kernel_launch(void* const* d_in, const int* in_sizes, int n_in,
                              void* d_out, int out_size, void* d_ws, size_t ws_size,
                              hipStream_t stream) {
  const float* x  = (const float*)d_in[0];
  const float* wq = (const float*)d_in[1];
  const float* bq = (const float*)d_in[2];
  const float* wk = (const float*)d_in[3];
  const float* bk = (const float*)d_in[4];
  const float* wv = (const float*)d_in[5];
  const float* bv = (const float*)d_in[6];
  const float* wo = (const float*)d_in[7];
  const float* bo = (const float*)d_in[8];
  float* out = (float*)d_out;

  char* p = (char*)d_ws;
  __bf16* xt    = (__bf16*)p; p += (size_t)BATCH * LLEN * CCH * 2;  // 32MB (reused as attn)
  __bf16* qt    = (__bf16*)p; p += (size_t)BATCH * LLEN * CCH * 2;  // 32MB
  __bf16* kcm   = (__bf16*)p; p += (size_t)BATCH * CCH * LLEN * 2;  // 32MB
  __bf16* vcm   = (__bf16*)p; p += (size_t)BATCH * CCH * LLEN * 2;  // 32MB
  __bf16* wqkvb = (__bf16*)p; p += (size_t)M1 * CCH * 2;
  __bf16* wob   = (__bf16*)p; p += (size_t)CCH * CCH * 2;
  float*  biasq = (float*)p;  p += (size_t)M1 * 4;
  float*  ksum  = (float*)p;  p += (size_t)BATCH * CCH * 4;
  float*  part  = (float*)p;  p += (size_t)8 * 64 * HD * HD * 4;    // 8MB
  float*  kvb   = (float*)p;  p += (size_t)64 * HD * HD * 4;        // 1MB
  float*  pks   = (float*)p;  p += (size_t)8 * 64 * 64 * 4;         // 128KB
  __bf16* attn  = xt;

  pack_w<<<1024, 256, 0, stream>>>(wq, wk, wv, wo, bq, bk, bv, wqkvb, wob, biasq);
  transpose_x<<<dim3(64, 8, BATCH), 256, 0, stream>>>(x, xt);
  gemm256<0><<<dim3(16, 6, BATCH), 512, 0, stream>>>(wqkvb, xt, biasq, qt, kcm, vcm, nullptr);
  kv_part_k<<<dim3(8, 64), 256, 0, stream>>>(kcm, vcm, part, pks);
  kv_red_k<<<1024, 256, 0, stream>>>(part, kvb);
  ksum_red_k<<<16, 256, 0, stream>>>(pks, ksum);
  apply_k<<<dim3(16, 64), 256, 0, stream>>>(qt, kvb, ksum, attn);
  gemm256<1><<<dim3(16, 2, BATCH), 512, 0, stream>>>(wob, attn, bo, nullptr, nullptr, nullptr, out);
}